// Round 13
// baseline (3595.969 us; speedup 1.0000x reference)
//
#include <hip/hip_runtime.h>
#include <cmath>

typedef unsigned short u16;
typedef __bf16 bf16;
typedef __attribute__((ext_vector_type(8))) bf16 bf16x8;
typedef __attribute__((ext_vector_type(4))) float f32x4;

#define DINL __device__ __forceinline__

#define BB 8
#define SS 1024
#define HH 768
#define LL 12
#define NHH 12
#define HDD 64
#define MM 8192
#define VV 50257

DINL u16 f2bf(float f) {
    unsigned int u = __builtin_bit_cast(unsigned int, f);
    u += 0x7fff + ((u >> 16) & 1);
    return (u16)(u >> 16);
}

DINL bf16x8 ld_bf8(const u16* p) { return *(const bf16x8*)p; }

typedef __attribute__((address_space(1))) unsigned int as1_u32;
typedef __attribute__((address_space(3))) unsigned int as3_u32;

DINL void gllds16(const void* g, void* l) {
    __builtin_amdgcn_global_load_lds((as1_u32*)g, (as3_u32*)l, 16, 0, 0);
}

#define BARRIER()                                   \
    do {                                            \
        asm volatile("" ::: "memory");              \
        __builtin_amdgcn_s_barrier();               \
        asm volatile("" ::: "memory");              \
    } while (0)

// sigmoid-form tanh-GELU: max |err| vs exact-erf gelu ~3e-4 (<< bf16 eps)
DINL float gelu_f(float v) {
    float u = v * (0.7978845608028654f + 0.035677408136300125f * v * v);
    return v * __builtin_amdgcn_rcpf(1.0f + __builtin_amdgcn_exp2f(-2.885390081777927f * u));
}

// XCD-aware block remap: all N-blocks of one M-panel land on the SAME XCD
DINL void xcd_remap(int gx, int& mTile, int& nTile) {
    int i = blockIdx.y * gx + blockIdx.x;
    int xcd = i & 7, j = i >> 3;
    nTile = j % gx;
    mTile = (j / gx) * 8 + xcd;
}

// ---------------- embedding: one block per token, float4 ----------------
__global__ __launch_bounds__(192) void k_embed(const int* __restrict__ ids,
                                               const float* __restrict__ tok,
                                               const float* __restrict__ pos,
                                               float* __restrict__ x) {
    int tk = blockIdx.x;
    int d4 = threadIdx.x;
    int s = tk & (SS - 1);
    int id = ids[tk];
    float4 tv = ((const float4*)(tok + (size_t)id * HH))[d4];
    float4 pv = ((const float4*)(pos + (size_t)s * HH))[d4];
    tv.x += pv.x; tv.y += pv.y; tv.z += pv.z; tv.w += pv.w;
    ((float4*)(x + (size_t)tk * HH))[d4] = tv;
}

// ---------------- transpose + f32->bf16 ----------------
__global__ __launch_bounds__(256) void k_tcvt(const float* __restrict__ src, u16* __restrict__ dst,
                                              int R, int C, size_t sstr, size_t dstr) {
    src += (size_t)blockIdx.z * sstr;
    dst += (size_t)blockIdx.z * dstr;
    __shared__ float t[32][33];
    int tx = threadIdx.x & 31, ty = threadIdx.x >> 5;
    int c0 = blockIdx.x * 32, r0 = blockIdx.y * 32;
#pragma unroll
    for (int p = 0; p < 4; p++)
        t[ty + p * 8][tx] = src[(size_t)(r0 + ty + p * 8) * C + c0 + tx];
    __syncthreads();
#pragma unroll
    for (int p = 0; p < 4; p++)
        dst[(size_t)(c0 + ty + p * 8) * R + r0 + tx] = f2bf(t[tx][ty + p * 8]);
}

// ---------------- layernorm ----------------
template <bool F32OUT>
__global__ __launch_bounds__(256) void k_ln(const float* __restrict__ x, const float* __restrict__ g,
                                            const float* __restrict__ b, void* __restrict__ outp,
                                            int nrows, int rs, int ro) {
    int w = threadIdx.x >> 6, lane = threadIdx.x & 63;
    int row = blockIdx.x * 4 + w;
    if (row >= nrows) return;
    const float4* xr = (const float4*)(x + ((size_t)row * rs + ro) * HH);
    float4 v[3];
    float s = 0.f, s2 = 0.f;
#pragma unroll
    for (int j = 0; j < 3; j++) {
        v[j] = xr[lane + 64 * j];
        s += v[j].x + v[j].y + v[j].z + v[j].w;
        s2 += v[j].x * v[j].x + v[j].y * v[j].y + v[j].z * v[j].z + v[j].w * v[j].w;
    }
#pragma unroll
    for (int off = 32; off; off >>= 1) {
        s += __shfl_xor(s, off, 64);
        s2 += __shfl_xor(s2, off, 64);
    }
    float mu = s * (1.0f / HH);
    float rstd = rsqrtf(s2 * (1.0f / HH) - mu * mu + 1e-5f);
#pragma unroll
    for (int j = 0; j < 3; j++) {
        int d4 = lane + 64 * j;
        float4 gv = ((const float4*)g)[d4];
        float4 bv = ((const float4*)b)[d4];
        float o0 = (v[j].x - mu) * rstd * gv.x + bv.x;
        float o1 = (v[j].y - mu) * rstd * gv.y + bv.y;
        float o2 = (v[j].z - mu) * rstd * gv.z + bv.z;
        float o3 = (v[j].w - mu) * rstd * gv.w + bv.w;
        if (F32OUT) {
            ((float4*)outp)[(size_t)row * (HH / 4) + d4] = make_float4(o0, o1, o2, o3);
        } else {
            ushort4 pk;
            pk.x = f2bf(o0); pk.y = f2bf(o1); pk.z = f2bf(o2); pk.w = f2bf(o3);
            *(ushort4*)((u16*)outp + (size_t)row * HH + d4 * 4) = pk;
        }
    }
}

// ---------------- bf16 GEMM 128x128, BK=32, 2-buffer SINGLE-BARRIER ring ----------------
// 32KB LDS -> 4 blocks/CU (16 waves/CU). Per K-step:
//   vmcnt(0) [tile kt, issued 1 iter ago] -> barrier -> stage(kt+1, other slot)
//   -> ds_read(kt) -> MFMA.
// Slot safety: other slot's readers (iter kt-1) finished before barrier(kt).
template <int EPI, int N, int K>
__global__ __launch_bounds__(256, 4) void k_gemm(const u16* __restrict__ A, const u16* __restrict__ BT,
                                                 const float* __restrict__ bias,
                                                 u16* __restrict__ obuf, u16* __restrict__ qb,
                                                 u16* __restrict__ kb, u16* __restrict__ vb) {
    __shared__ u16 As[2][128 * 32];
    __shared__ u16 Bs[2][128 * 32];
    const int t = threadIdx.x, w = t >> 6, lane = t & 63;
    const int l15 = lane & 15, l4 = lane >> 4;
    const int wr = w >> 1, wc = w & 1;
    int mT, nT;
    xcd_remap(gridDim.x, mT, nT);
    const int m0 = mT * 128, n0 = nT * 128;
    const int KT = K >> 5;

    f32x4 acc[4][4] = {};

    auto stage = [&](int buf, int kt) {
#pragma unroll
        for (int i = 0; i < 2; i++) {
            int idx = w * 2 + i;
            int row = idx * 16 + (lane >> 2);
            int kc = kt * 32 + (((lane & 3) ^ ((lane >> 3) & 3)) * 8);
            gllds16(A + (size_t)(m0 + row) * K + kc, &As[buf][idx * 512]);
            gllds16(BT + (size_t)(n0 + row) * K + kc, &Bs[buf][idx * 512]);
        }
    };

    stage(0, 0);
    const int sw = (l15 >> 1) & 3;

    for (int kt = 0; kt < KT; ++kt) {
        asm volatile("s_waitcnt vmcnt(0)" ::: "memory");   // tile kt landed (1-iter lead)
        BARRIER();
        if (kt + 1 < KT) stage((kt + 1) & 1, kt + 1);      // head start for next tile

        const u16* ap = As[kt & 1];
        const u16* bp = Bs[kt & 1];
        bf16x8 af[4], bfr[4];
#pragma unroll
        for (int i = 0; i < 4; i++) af[i] = ld_bf8(ap + (wr * 64 + i * 16 + l15) * 32 + ((l4 ^ sw) * 8));
#pragma unroll
        for (int j = 0; j < 4; j++) bfr[j] = ld_bf8(bp + (wc * 64 + j * 16 + l15) * 32 + ((l4 ^ sw) * 8));

        __builtin_amdgcn_s_setprio(1);
#pragma unroll
        for (int i = 0; i < 4; i++)
#pragma unroll
            for (int j = 0; j < 4; j++)
                acc[i][j] = __builtin_amdgcn_mfma_f32_16x16x32_bf16(af[i], bfr[j], acc[i][j], 0, 0, 0);
        __builtin_amdgcn_s_setprio(0);
    }

#pragma unroll
    for (int i = 0; i < 4; i++) {
#pragma unroll
        for (int j = 0; j < 4; j++) {
#pragma unroll
            for (int r = 0; r < 4; r++) {
                int row = m0 + wr * 64 + i * 16 + l4 * 4 + r;
                int n = n0 + wc * 64 + j * 16 + l15;
                float v = acc[i][j][r] + bias[n];
                if (EPI == 0) {
                    int sg = n / HH, wi = n % HH;
                    int h = wi >> 6, d = wi & 63;
                    int bi = row >> 10, s = row & (SS - 1);
                    size_t bh = (size_t)(bi * NHH + h);
                    if (sg == 0)
                        qb[(bh * SS + s) * HDD + d] = f2bf(v * 0.1803368801111204f);  // 0.125*log2e
                    else if (sg == 1)
                        kb[(bh * SS + s) * HDD + d] = f2bf(v);
                    else
                        vb[(bh * HDD + d) * SS + s] = f2bf(v);
                } else {
                    obuf[(size_t)row * N + n] = f2bf(gelu_f(v));
                }
            }
        }
    }
}

// ---------------- bf16 GEMM 128x64, BK=32, 3-buffer SINGLE-BARRIER ring ----------------
template <int K>
__global__ __launch_bounds__(256) void k_gemm64(const u16* __restrict__ A, const u16* __restrict__ BT,
                                                const float* __restrict__ bias, float* __restrict__ xio) {
    __shared__ u16 As[3][128 * 32];
    __shared__ u16 Bs[3][64 * 32];
    const int t = threadIdx.x, w = t >> 6, lane = t & 63;
    const int l15 = lane & 15, l4 = lane >> 4;
    const int wr = w >> 1, wc = w & 1;
    int mT, nT;
    xcd_remap(gridDim.x, mT, nT);
    const int m0 = mT * 128, n0 = nT * 64;
    const int KT = K >> 5;
    const int N = 768;

    f32x4 acc[4][2] = {};

    auto stage = [&](int buf, int kt) {
        int rr = lane >> 2;
        int kc = kt * 32 + (((lane & 3) ^ ((lane >> 3) & 3)) * 8);
#pragma unroll
        for (int i = 0; i < 2; i++) {
            int idx = w * 2 + i;
            gllds16(A + (size_t)(m0 + idx * 16 + rr) * K + kc, &As[buf][idx * 512]);
        }
        gllds16(BT + (size_t)(n0 + w * 16 + rr) * K + kc, &Bs[buf][w * 512]);
    };

    stage(0, 0);
    stage(1, 1);
    const int sw = (l15 >> 1) & 3;

    for (int kt = 0; kt < KT; ++kt) {
        if (kt + 1 < KT) asm volatile("s_waitcnt vmcnt(3)" ::: "memory");
        else             asm volatile("s_waitcnt vmcnt(0)" ::: "memory");
        BARRIER();

        const u16* ap = As[kt % 3];
        const u16* bp = Bs[kt % 3];
        bf16x8 af[4], bfr[2];
#pragma unroll
        for (int i = 0; i < 4; i++) af[i] = ld_bf8(ap + (wr * 64 + i * 16 + l15) * 32 + ((l4 ^ sw) * 8));
#pragma unroll
        for (int j = 0; j < 2; j++) bfr[j] = ld_bf8(bp + (wc * 32 + j * 16 + l15) * 32 + ((l4 ^ sw) * 8));

        if (kt + 2 < KT) stage((kt + 2) % 3, kt + 2);

        __builtin_amdgcn_s_setprio(1);
#pragma unroll
        for (int i = 0; i < 4; i++)
#pragma unroll
            for (int j = 0; j < 2; j++)
                acc[i][j] = __builtin_amdgcn_mfma_f32_16x16x32_bf16(af[i], bfr[j], acc[i][j], 0, 0, 0);
        __builtin_amdgcn_s_setprio(0);
    }

#pragma unroll
    for (int i = 0; i < 4; i++) {
#pragma unroll
        for (int j = 0; j < 2; j++) {
#pragma unroll
            for (int r = 0; r < 4; r++) {
                int row = m0 + wr * 64 + i * 16 + l4 * 4 + r;
                int n = n0 + wc * 32 + j * 16 + l15;
                xio[(size_t)row * N + n] += acc[i][j][r] + bias[n];
            }
        }
    }
}

// ---------------- flash attention: swapped QK^T (S^T fragments), lane-local softmax ----------------
__global__ __launch_bounds__(256) void k_attn(const u16* __restrict__ q, const u16* __restrict__ k,
                                              const u16* __restrict__ vt, u16* __restrict__ o) {
    int qt = 15 - blockIdx.x;
    int bh = blockIdx.y;
    int w = threadIdx.x >> 6, lane = threadIdx.x & 63;
    int l15 = lane & 15, l4 = lane >> 4;

    __shared__ u16 Ks[3][64 * 64];
    __shared__ u16 Vs[2][64 * 64];
    __shared__ u16 pl[4][16 * 72];
    u16* pw = pl[w];

    const size_t bhq = (size_t)bh * SS * HDD;
    int qrow0 = qt * 64 + w * 16;
    const int myq = qrow0 + l15;

    auto stageK = [&](int slot, int kvb) {
#pragma unroll
        for (int i = 0; i < 2; i++) {
            int rl = w * 16 + i * 8 + (lane >> 3);
            int sc = ((lane & 7) ^ (rl & 7)) * 8;
            gllds16(k + bhq + (size_t)(kvb * 64 + rl) * HDD + sc, &Ks[slot][(w * 16 + i * 8) * 64]);
        }
    };
    auto stageV = [&](int slot, int kvb) {
#pragma unroll
        for (int i = 0; i < 2; i++) {
            int rl = w * 16 + i * 8 + (lane >> 3);
            int sc = ((lane & 7) ^ (rl & 7)) * 8;
            gllds16(vt + ((size_t)bh * HDD + rl) * SS + kvb * 64 + sc, &Vs[slot][(w * 16 + i * 8) * 64]);
        }
    };

    bf16x8 aq[2];
#pragma unroll
    for (int ks = 0; ks < 2; ks++)
        aq[ks] = ld_bf8(q + bhq + (size_t)(qrow0 + l15) * HDD + ks * 32 + l4 * 8);

    f32x4 acc[4] = {};
    float mrun = -1e30f, psum = 0.f;

    stageK(0, 0);
    stageV(0, 0);
    if (qt >= 1) stageK(1, 1);

    for (int kvb = 0; kvb <= qt; ++kvb) {
        if (kvb < qt) asm volatile("s_waitcnt vmcnt(2)" ::: "memory");
        else          asm volatile("s_waitcnt vmcnt(0)" ::: "memory");
        BARRIER();
        if (kvb + 1 <= qt) stageV((kvb + 1) & 1, kvb + 1);
        if (kvb + 2 <= qt) stageK((kvb + 2) % 3, kvb + 2);

        const u16* kp = Ks[kvb % 3];
        const u16* vp = Vs[kvb & 1];

        f32x4 s[4] = {};
#pragma unroll
        for (int c = 0; c < 4; c++) {
#pragma unroll
            for (int ks = 0; ks < 2; ks++) {
                bf16x8 kf = ld_bf8(kp + (c * 16 + l15) * 64 + ((ks * 4 + l4) ^ (l15 & 7)) * 8);
                s[c] = __builtin_amdgcn_mfma_f32_16x16x32_bf16(kf, aq[ks], s[c], 0, 0, 0);
            }
        }
        if (kvb == qt) {
            int kbase = kvb * 64 + l4 * 4;
#pragma unroll
            for (int c = 0; c < 4; c++)
#pragma unroll
                for (int r = 0; r < 4; r++)
                    if (kbase + c * 16 + r > myq) s[c][r] = -1803.3688f;
        }
        float lmax = s[0][0];
#pragma unroll
        for (int c = 0; c < 4; c++)
#pragma unroll
            for (int r = 0; r < 4; r++) lmax = fmaxf(lmax, s[c][r]);
        int ok = (lmax <= mrun + 11.5416f) ? 1 : 0;
        if (!__all(ok)) {
            lmax = fmaxf(lmax, __shfl_xor(lmax, 16, 64));
            lmax = fmaxf(lmax, __shfl_xor(lmax, 32, 64));
            float mnew = fmaxf(mrun, lmax);
            float ef = __builtin_amdgcn_exp2f(mrun - mnew);
            mrun = mnew;
            psum *= ef;
            float ef4[4];
#pragma unroll
            for (int r = 0; r < 4; r++) ef4[r] = __shfl(ef, l4 * 4 + r, 64);
#pragma unroll
            for (int cd = 0; cd < 4; cd++)
#pragma unroll
                for (int r = 0; r < 4; r++) acc[cd][r] *= ef4[r];
        }
#pragma unroll
        for (int c = 0; c < 4; c++) {
            float p0 = __builtin_amdgcn_exp2f(s[c][0] - mrun);
            float p1 = __builtin_amdgcn_exp2f(s[c][1] - mrun);
            float p2 = __builtin_amdgcn_exp2f(s[c][2] - mrun);
            float p3 = __builtin_amdgcn_exp2f(s[c][3] - mrun);
            psum += (p0 + p1) + (p2 + p3);
            ushort4 p4;
            p4.x = f2bf(p0); p4.y = f2bf(p1); p4.z = f2bf(p2); p4.w = f2bf(p3);
            *(ushort4*)(pw + l15 * 72 + c * 16 + l4 * 4) = p4;
        }
#pragma unroll
        for (int ks = 0; ks < 2; ks++) {
            bf16x8 pa = ld_bf8(pw + l15 * 72 + ks * 32 + l4 * 8);
#pragma unroll
            for (int cd = 0; cd < 4; cd++) {
                bf16x8 vf = ld_bf8(vp + (cd * 16 + l15) * 64 + ((ks * 4 + l4) ^ (l15 & 7)) * 8);
                acc[cd] = __builtin_amdgcn_mfma_f32_16x16x32_bf16(pa, vf, acc[cd], 0, 0, 0);
            }
        }
    }

    psum += __shfl_xor(psum, 16, 64);
    psum += __shfl_xor(psum, 32, 64);
    float ps4[4];
#pragma unroll
    for (int r = 0; r < 4; r++) ps4[r] = __shfl(psum, l4 * 4 + r, 64);

    int b = bh / NHH, h = bh % NHH;
#pragma unroll
    for (int cd = 0; cd < 4; cd++) {
#pragma unroll
        for (int r = 0; r < 4; r++) {
            int qi = qrow0 + l4 * 4 + r;
            float ov = acc[cd][r] / ps4[r];
            o[((size_t)b * SS + qi) * HH + h * HDD + cd * 16 + l15] = f2bf(ov);
        }
    }
}

// ---------------- logits ----------------
__global__ __launch_bounds__(256) void k_logits(const float* __restrict__ enc,
                                                const float* __restrict__ tok,
                                                float* __restrict__ out) {
    int w = threadIdx.x >> 6, lane = threadIdx.x & 63;
    int v = blockIdx.x * 4 + w;
    if (v >= VV) return;
    const float4* tr = (const float4*)(tok + (size_t)v * HH);
    float a[8];
#pragma unroll
    for (int b = 0; b < 8; b++) a[b] = 0.f;
#pragma unroll
    for (int j = 0; j < 3; j++) {
        float4 t4 = tr[lane + 64 * j];
#pragma unroll
        for (int b = 0; b < 8; b++) {
            float4 e4 = *(const float4*)(enc + (size_t)b * HH + (lane + 64 * j) * 4);
            a[b] += t4.x * e4.x + t4.y * e4.y + t4.z * e4.z + t4.w * e4.w;
        }
    }
#pragma unroll
    for (int off = 32; off; off >>= 1)
#pragma unroll
        for (int b = 0; b < 8; b++) a[b] += __shfl_xor(a[b], off, 64);
    if (lane == 0) {
#pragma unroll
        for (int b = 0; b < 8; b++) out[(size_t)b * VV + v] = a[b];
    }
}

extern "C" void kernel_launch(void* const* d_in, const int* in_sizes, int n_in,
                              void* d_out, int out_size, void* d_ws, size_t ws_size,
                              hipStream_t stream) {
    const int* ids = (const int*)d_in[0];
    const float* tok = (const float*)d_in[1];
    const float* pos = (const float*)d_in[2];
    const float* ln1g = (const float*)d_in[3];
    const float* ln1b = (const float*)d_in[4];
    const float* wat = (const float*)d_in[5];
    const float* bat = (const float*)d_in[6];
    const float* wou = (const float*)d_in[7];
    const float* bou = (const float*)d_in[8];
    const float* ln2g = (const float*)d_in[9];
    const float* ln2b = (const float*)d_in[10];
    const float* w1 = (const float*)d_in[11];
    const float* b1 = (const float*)d_in[12];
    const float* w2 = (const float*)d_in[13];
    const float* b2 = (const float*)d_in[14];
    const float* lnfg = (const float*)d_in[15];
    const float* lnfb = (const float*)d_in[16];

    char* ws = (char*)d_ws;
    float* xw = (float*)(ws + 0);                 // f32 residual  [8192,768]
    u16* nb = (u16*)(ws + 25165824);              // bf16 LN out
    u16* qb = (u16*)(ws + 37748736);              // q*0.125*log2e [B,NH,S,HD]
    u16* kb = (u16*)(ws + 50331648);              // k [B,NH,S,HD]
    u16* vb = (u16*)(ws + 62914560);              // v^T [B,NH,HD,S]
    u16* ab = (u16*)(ws + 75497472);              // attn out
    u16* hb = (u16*)(ws + 88080384);              // mlp mid [8192,3072]
    u16* wt = (u16*)(ws + 138412032);             // bf16 transposed weights
    const size_t LSTR = 7077888;
    const size_t WAO = 0, WOO = 1769472, W1O = 2359296, W2O = 4718592;

    float* outf = (float*)d_out;
    float* enc = outf + (size_t)BB * VV;

    k_embed<<<MM, 192, 0, stream>>>(ids, tok, pos, xw);
    k_tcvt<<<dim3(72, 24, 12), 256, 0, stream>>>(wat, wt + WAO, 768, 2304, (size_t)768 * 2304, LSTR);
    k_tcvt<<<dim3(24, 24, 12), 256, 0, stream>>>(wou, wt + WOO, 768, 768, (size_t)768 * 768, LSTR);
    k_tcvt<<<dim3(96, 24, 12), 256, 0, stream>>>(w1, wt + W1O, 768, 3072, (size_t)768 * 3072, LSTR);
    k_tcvt<<<dim3(24, 96, 12), 256, 0, stream>>>(w2, wt + W2O, 3072, 768, (size_t)3072 * 768, LSTR);

    for (int l = 0; l < LL; l++) {
        const u16* wl = wt + (size_t)l * LSTR;
        k_ln<false><<<MM / 4, 256, 0, stream>>>(xw, ln1g + l * HH, ln1b + l * HH, nb, MM, 1, 0);
        k_gemm<0, 2304, 768><<<dim3(18, 64), 256, 0, stream>>>(nb, wl + WAO, bat + (size_t)l * 2304,
                                                               nullptr, qb, kb, vb);
        k_attn<<<dim3(16, 96), 256, 0, stream>>>(qb, kb, vb, ab);
        k_gemm64<768><<<dim3(12, 64), 256, 0, stream>>>(ab, wl + WOO, bou + (size_t)l * HH, xw);
        k_ln<false><<<MM / 4, 256, 0, stream>>>(xw, ln2g + l * HH, ln2b + l * HH, nb, MM, 1, 0);
        k_gemm<2, 3072, 768><<<dim3(24, 64), 256, 0, stream>>>(nb, wl + W1O, b1 + (size_t)l * 3072,
                                                               hb, nullptr, nullptr, nullptr);
        k_gemm64<3072><<<dim3(12, 64), 256, 0, stream>>>(hb, wl + W2O, b2 + (size_t)l * HH, xw);
    }
    k_ln<true><<<2, 256, 0, stream>>>(xw, lnfg, lnfb, enc, BB, SS, SS - 1);
    k_logits<<<(VV + 3) / 4, 256, 0, stream>>>(enc, tok, outf);
}

// Round 14
// 3589.465 us; speedup vs baseline: 1.0018x; 1.0018x over previous
//
#include <hip/hip_runtime.h>
#include <cmath>

typedef unsigned short u16;
typedef __bf16 bf16;
typedef __attribute__((ext_vector_type(8))) bf16 bf16x8;
typedef __attribute__((ext_vector_type(4))) float f32x4;

#define DINL __device__ __forceinline__

#define BB 8
#define SS 1024
#define HH 768
#define LL 12
#define NHH 12
#define HDD 64
#define MM 8192
#define VV 50257

DINL u16 f2bf(float f) {
    unsigned int u = __builtin_bit_cast(unsigned int, f);
    u += 0x7fff + ((u >> 16) & 1);
    return (u16)(u >> 16);
}

DINL bf16x8 ld_bf8(const u16* p) { return *(const bf16x8*)p; }

typedef __attribute__((address_space(1))) unsigned int as1_u32;
typedef __attribute__((address_space(3))) unsigned int as3_u32;

DINL void gllds16(const void* g, void* l) {
    __builtin_amdgcn_global_load_lds((as1_u32*)g, (as3_u32*)l, 16, 0, 0);
}

#define BARRIER()                                   \
    do {                                            \
        asm volatile("" ::: "memory");              \
        __builtin_amdgcn_s_barrier();               \
        asm volatile("" ::: "memory");              \
    } while (0)

// sigmoid-form tanh-GELU: max |err| vs exact-erf gelu ~3e-4 (<< bf16 eps)
DINL float gelu_f(float v) {
    float u = v * (0.7978845608028654f + 0.035677408136300125f * v * v);
    return v * __builtin_amdgcn_rcpf(1.0f + __builtin_amdgcn_exp2f(-2.885390081777927f * u));
}

// XCD-aware block remap: all N-blocks of one M-panel land on the SAME XCD
DINL void xcd_remap(int gx, int& mTile, int& nTile) {
    int i = blockIdx.y * gx + blockIdx.x;
    int xcd = i & 7, j = i >> 3;
    nTile = j % gx;
    mTile = (j / gx) * 8 + xcd;
}

// ---------------- embedding: one block per token, float4 ----------------
__global__ __launch_bounds__(192) void k_embed(const int* __restrict__ ids,
                                               const float* __restrict__ tok,
                                               const float* __restrict__ pos,
                                               float* __restrict__ x) {
    int tk = blockIdx.x;
    int d4 = threadIdx.x;
    int s = tk & (SS - 1);
    int id = ids[tk];
    float4 tv = ((const float4*)(tok + (size_t)id * HH))[d4];
    float4 pv = ((const float4*)(pos + (size_t)s * HH))[d4];
    tv.x += pv.x; tv.y += pv.y; tv.z += pv.z; tv.w += pv.w;
    ((float4*)(x + (size_t)tk * HH))[d4] = tv;
}

// ---------------- transpose + f32->bf16 ----------------
__global__ __launch_bounds__(256) void k_tcvt(const float* __restrict__ src, u16* __restrict__ dst,
                                              int R, int C, size_t sstr, size_t dstr) {
    src += (size_t)blockIdx.z * sstr;
    dst += (size_t)blockIdx.z * dstr;
    __shared__ float t[32][33];
    int tx = threadIdx.x & 31, ty = threadIdx.x >> 5;
    int c0 = blockIdx.x * 32, r0 = blockIdx.y * 32;
#pragma unroll
    for (int p = 0; p < 4; p++)
        t[ty + p * 8][tx] = src[(size_t)(r0 + ty + p * 8) * C + c0 + tx];
    __syncthreads();
#pragma unroll
    for (int p = 0; p < 4; p++)
        dst[(size_t)(c0 + ty + p * 8) * R + r0 + tx] = f2bf(t[tx][ty + p * 8]);
}

// ---------------- layernorm ----------------
template <bool F32OUT>
__global__ __launch_bounds__(256) void k_ln(const float* __restrict__ x, const float* __restrict__ g,
                                            const float* __restrict__ b, void* __restrict__ outp,
                                            int nrows, int rs, int ro) {
    int w = threadIdx.x >> 6, lane = threadIdx.x & 63;
    int row = blockIdx.x * 4 + w;
    if (row >= nrows) return;
    const float4* xr = (const float4*)(x + ((size_t)row * rs + ro) * HH);
    float4 v[3];
    float s = 0.f, s2 = 0.f;
#pragma unroll
    for (int j = 0; j < 3; j++) {
        v[j] = xr[lane + 64 * j];
        s += v[j].x + v[j].y + v[j].z + v[j].w;
        s2 += v[j].x * v[j].x + v[j].y * v[j].y + v[j].z * v[j].z + v[j].w * v[j].w;
    }
#pragma unroll
    for (int off = 32; off; off >>= 1) {
        s += __shfl_xor(s, off, 64);
        s2 += __shfl_xor(s2, off, 64);
    }
    float mu = s * (1.0f / HH);
    float rstd = rsqrtf(s2 * (1.0f / HH) - mu * mu + 1e-5f);
#pragma unroll
    for (int j = 0; j < 3; j++) {
        int d4 = lane + 64 * j;
        float4 gv = ((const float4*)g)[d4];
        float4 bv = ((const float4*)b)[d4];
        float o0 = (v[j].x - mu) * rstd * gv.x + bv.x;
        float o1 = (v[j].y - mu) * rstd * gv.y + bv.y;
        float o2 = (v[j].z - mu) * rstd * gv.z + bv.z;
        float o3 = (v[j].w - mu) * rstd * gv.w + bv.w;
        if (F32OUT) {
            ((float4*)outp)[(size_t)row * (HH / 4) + d4] = make_float4(o0, o1, o2, o3);
        } else {
            ushort4 pk;
            pk.x = f2bf(o0); pk.y = f2bf(o1); pk.z = f2bf(o2); pk.w = f2bf(o3);
            *(ushort4*)((u16*)outp + (size_t)row * HH + d4 * 4) = pk;
        }
    }
}

// ---------------- bf16 GEMM 128x128, BK=32, hybrid A-ring3 / B-ring2 ----------------
// 40KB LDS -> 4 blocks/CU. A gets 2-iter prefetch lead (HBM-streamed), B 1-iter
// (L2-hot via XCD remap). Issue order per iter: B(kt+1) then A(kt+2); FIFO at top
// of iter kt = [A(kt), B(kt), A(kt+1)] -> vmcnt(2) waits exactly tile kt.
template <int EPI, int N, int K>
__global__ __launch_bounds__(256, 4) void k_gemm(const u16* __restrict__ A, const u16* __restrict__ BT,
                                                 const float* __restrict__ bias,
                                                 u16* __restrict__ obuf, u16* __restrict__ qb,
                                                 u16* __restrict__ kb, u16* __restrict__ vb) {
    __shared__ u16 As[3][128 * 32];
    __shared__ u16 Bs[2][128 * 32];
    const int t = threadIdx.x, w = t >> 6, lane = t & 63;
    const int l15 = lane & 15, l4 = lane >> 4;
    const int wr = w >> 1, wc = w & 1;
    int mT, nT;
    xcd_remap(gridDim.x, mT, nT);
    const int m0 = mT * 128, n0 = nT * 128;
    const int KT = K >> 5;

    f32x4 acc[4][4] = {};

    auto stageA = [&](int buf, int kt) {
#pragma unroll
        for (int i = 0; i < 2; i++) {
            int idx = w * 2 + i;
            int row = idx * 16 + (lane >> 2);
            int kc = kt * 32 + (((lane & 3) ^ ((lane >> 3) & 3)) * 8);
            gllds16(A + (size_t)(m0 + row) * K + kc, &As[buf][idx * 512]);
        }
    };
    auto stageB = [&](int buf, int kt) {
#pragma unroll
        for (int i = 0; i < 2; i++) {
            int idx = w * 2 + i;
            int row = idx * 16 + (lane >> 2);
            int kc = kt * 32 + (((lane & 3) ^ ((lane >> 3) & 3)) * 8);
            gllds16(BT + (size_t)(n0 + row) * K + kc, &Bs[buf][idx * 512]);
        }
    };

    // prologue FIFO: A(0), B(0), A(1)
    stageA(0, 0);
    stageB(0, 0);
    stageA(1, 1);
    const int sw = (l15 >> 1) & 3;

    for (int kt = 0; kt < KT; ++kt) {
        if (kt < KT - 1) asm volatile("s_waitcnt vmcnt(2)" ::: "memory");  // A(kt)+B(kt) done, A(kt+1) in flight
        else             asm volatile("s_waitcnt vmcnt(0)" ::: "memory");
        BARRIER();
        if (kt + 1 < KT) stageB((kt + 1) & 1, kt + 1);
        if (kt + 2 < KT) stageA((kt + 2) % 3, kt + 2);

        const u16* ap = As[kt % 3];
        const u16* bp = Bs[kt & 1];
        bf16x8 af[4], bfr[4];
#pragma unroll
        for (int i = 0; i < 4; i++) af[i] = ld_bf8(ap + (wr * 64 + i * 16 + l15) * 32 + ((l4 ^ sw) * 8));
#pragma unroll
        for (int j = 0; j < 4; j++) bfr[j] = ld_bf8(bp + (wc * 64 + j * 16 + l15) * 32 + ((l4 ^ sw) * 8));

        __builtin_amdgcn_s_setprio(1);
#pragma unroll
        for (int i = 0; i < 4; i++)
#pragma unroll
            for (int j = 0; j < 4; j++)
                acc[i][j] = __builtin_amdgcn_mfma_f32_16x16x32_bf16(af[i], bfr[j], acc[i][j], 0, 0, 0);
        __builtin_amdgcn_s_setprio(0);
    }

#pragma unroll
    for (int i = 0; i < 4; i++) {
#pragma unroll
        for (int j = 0; j < 4; j++) {
#pragma unroll
            for (int r = 0; r < 4; r++) {
                int row = m0 + wr * 64 + i * 16 + l4 * 4 + r;
                int n = n0 + wc * 64 + j * 16 + l15;
                float v = acc[i][j][r] + bias[n];
                if (EPI == 0) {
                    int sg = n / HH, wi = n % HH;
                    int h = wi >> 6, d = wi & 63;
                    int bi = row >> 10, s = row & (SS - 1);
                    size_t bh = (size_t)(bi * NHH + h);
                    if (sg == 0)
                        qb[(bh * SS + s) * HDD + d] = f2bf(v * 0.1803368801111204f);  // 0.125*log2e
                    else if (sg == 1)
                        kb[(bh * SS + s) * HDD + d] = f2bf(v);
                    else
                        vb[(bh * HDD + d) * SS + s] = f2bf(v);
                } else {
                    obuf[(size_t)row * N + n] = f2bf(gelu_f(v));
                }
            }
        }
    }
}

// ---------------- bf16 GEMM 128x64, BK=32, 3-buffer SINGLE-BARRIER ring ----------------
template <int K>
__global__ __launch_bounds__(256) void k_gemm64(const u16* __restrict__ A, const u16* __restrict__ BT,
                                                const float* __restrict__ bias, float* __restrict__ xio) {
    __shared__ u16 As[3][128 * 32];
    __shared__ u16 Bs[3][64 * 32];
    const int t = threadIdx.x, w = t >> 6, lane = t & 63;
    const int l15 = lane & 15, l4 = lane >> 4;
    const int wr = w >> 1, wc = w & 1;
    int mT, nT;
    xcd_remap(gridDim.x, mT, nT);
    const int m0 = mT * 128, n0 = nT * 64;
    const int KT = K >> 5;
    const int N = 768;

    f32x4 acc[4][2] = {};

    auto stage = [&](int buf, int kt) {
        int rr = lane >> 2;
        int kc = kt * 32 + (((lane & 3) ^ ((lane >> 3) & 3)) * 8);
#pragma unroll
        for (int i = 0; i < 2; i++) {
            int idx = w * 2 + i;
            gllds16(A + (size_t)(m0 + idx * 16 + rr) * K + kc, &As[buf][idx * 512]);
        }
        gllds16(BT + (size_t)(n0 + w * 16 + rr) * K + kc, &Bs[buf][w * 512]);
    };

    stage(0, 0);
    stage(1, 1);
    const int sw = (l15 >> 1) & 3;

    for (int kt = 0; kt < KT; ++kt) {
        if (kt + 1 < KT) asm volatile("s_waitcnt vmcnt(3)" ::: "memory");
        else             asm volatile("s_waitcnt vmcnt(0)" ::: "memory");
        BARRIER();

        const u16* ap = As[kt % 3];
        const u16* bp = Bs[kt % 3];
        bf16x8 af[4], bfr[2];
#pragma unroll
        for (int i = 0; i < 4; i++) af[i] = ld_bf8(ap + (wr * 64 + i * 16 + l15) * 32 + ((l4 ^ sw) * 8));
#pragma unroll
        for (int j = 0; j < 2; j++) bfr[j] = ld_bf8(bp + (wc * 32 + j * 16 + l15) * 32 + ((l4 ^ sw) * 8));

        if (kt + 2 < KT) stage((kt + 2) % 3, kt + 2);

        __builtin_amdgcn_s_setprio(1);
#pragma unroll
        for (int i = 0; i < 4; i++)
#pragma unroll
            for (int j = 0; j < 2; j++)
                acc[i][j] = __builtin_amdgcn_mfma_f32_16x16x32_bf16(af[i], bfr[j], acc[i][j], 0, 0, 0);
        __builtin_amdgcn_s_setprio(0);
    }

#pragma unroll
    for (int i = 0; i < 4; i++) {
#pragma unroll
        for (int j = 0; j < 2; j++) {
#pragma unroll
            for (int r = 0; r < 4; r++) {
                int row = m0 + wr * 64 + i * 16 + l4 * 4 + r;
                int n = n0 + wc * 32 + j * 16 + l15;
                xio[(size_t)row * N + n] += acc[i][j][r] + bias[n];
            }
        }
    }
}

// ---------------- flash attention: swapped QK^T (S^T fragments), lane-local softmax ----------------
__global__ __launch_bounds__(256) void k_attn(const u16* __restrict__ q, const u16* __restrict__ k,
                                              const u16* __restrict__ vt, u16* __restrict__ o) {
    int qt = 15 - blockIdx.x;
    int bh = blockIdx.y;
    int w = threadIdx.x >> 6, lane = threadIdx.x & 63;
    int l15 = lane & 15, l4 = lane >> 4;

    __shared__ u16 Ks[3][64 * 64];
    __shared__ u16 Vs[2][64 * 64];
    __shared__ u16 pl[4][16 * 72];
    u16* pw = pl[w];

    const size_t bhq = (size_t)bh * SS * HDD;
    int qrow0 = qt * 64 + w * 16;
    const int myq = qrow0 + l15;

    auto stageK = [&](int slot, int kvb) {
#pragma unroll
        for (int i = 0; i < 2; i++) {
            int rl = w * 16 + i * 8 + (lane >> 3);
            int sc = ((lane & 7) ^ (rl & 7)) * 8;
            gllds16(k + bhq + (size_t)(kvb * 64 + rl) * HDD + sc, &Ks[slot][(w * 16 + i * 8) * 64]);
        }
    };
    auto stageV = [&](int slot, int kvb) {
#pragma unroll
        for (int i = 0; i < 2; i++) {
            int rl = w * 16 + i * 8 + (lane >> 3);
            int sc = ((lane & 7) ^ (rl & 7)) * 8;
            gllds16(vt + ((size_t)bh * HDD + rl) * SS + kvb * 64 + sc, &Vs[slot][(w * 16 + i * 8) * 64]);
        }
    };

    bf16x8 aq[2];
#pragma unroll
    for (int ks = 0; ks < 2; ks++)
        aq[ks] = ld_bf8(q + bhq + (size_t)(qrow0 + l15) * HDD + ks * 32 + l4 * 8);

    f32x4 acc[4] = {};
    float mrun = -1e30f, psum = 0.f;

    stageK(0, 0);
    stageV(0, 0);
    if (qt >= 1) stageK(1, 1);

    for (int kvb = 0; kvb <= qt; ++kvb) {
        if (kvb < qt) asm volatile("s_waitcnt vmcnt(2)" ::: "memory");
        else          asm volatile("s_waitcnt vmcnt(0)" ::: "memory");
        BARRIER();
        if (kvb + 1 <= qt) stageV((kvb + 1) & 1, kvb + 1);
        if (kvb + 2 <= qt) stageK((kvb + 2) % 3, kvb + 2);

        const u16* kp = Ks[kvb % 3];
        const u16* vp = Vs[kvb & 1];

        f32x4 s[4] = {};
#pragma unroll
        for (int c = 0; c < 4; c++) {
#pragma unroll
            for (int ks = 0; ks < 2; ks++) {
                bf16x8 kf = ld_bf8(kp + (c * 16 + l15) * 64 + ((ks * 4 + l4) ^ (l15 & 7)) * 8);
                s[c] = __builtin_amdgcn_mfma_f32_16x16x32_bf16(kf, aq[ks], s[c], 0, 0, 0);
            }
        }
        if (kvb == qt) {
            int kbase = kvb * 64 + l4 * 4;
#pragma unroll
            for (int c = 0; c < 4; c++)
#pragma unroll
                for (int r = 0; r < 4; r++)
                    if (kbase + c * 16 + r > myq) s[c][r] = -1803.3688f;
        }
        float lmax = s[0][0];
#pragma unroll
        for (int c = 0; c < 4; c++)
#pragma unroll
            for (int r = 0; r < 4; r++) lmax = fmaxf(lmax, s[c][r]);
        int ok = (lmax <= mrun + 11.5416f) ? 1 : 0;
        if (!__all(ok)) {
            lmax = fmaxf(lmax, __shfl_xor(lmax, 16, 64));
            lmax = fmaxf(lmax, __shfl_xor(lmax, 32, 64));
            float mnew = fmaxf(mrun, lmax);
            float ef = __builtin_amdgcn_exp2f(mrun - mnew);
            mrun = mnew;
            psum *= ef;
            float ef4[4];
#pragma unroll
            for (int r = 0; r < 4; r++) ef4[r] = __shfl(ef, l4 * 4 + r, 64);
#pragma unroll
            for (int cd = 0; cd < 4; cd++)
#pragma unroll
                for (int r = 0; r < 4; r++) acc[cd][r] *= ef4[r];
        }
#pragma unroll
        for (int c = 0; c < 4; c++) {
            float p0 = __builtin_amdgcn_exp2f(s[c][0] - mrun);
            float p1 = __builtin_amdgcn_exp2f(s[c][1] - mrun);
            float p2 = __builtin_amdgcn_exp2f(s[c][2] - mrun);
            float p3 = __builtin_amdgcn_exp2f(s[c][3] - mrun);
            psum += (p0 + p1) + (p2 + p3);
            ushort4 p4;
            p4.x = f2bf(p0); p4.y = f2bf(p1); p4.z = f2bf(p2); p4.w = f2bf(p3);
            *(ushort4*)(pw + l15 * 72 + c * 16 + l4 * 4) = p4;
        }
#pragma unroll
        for (int ks = 0; ks < 2; ks++) {
            bf16x8 pa = ld_bf8(pw + l15 * 72 + ks * 32 + l4 * 8);
#pragma unroll
            for (int cd = 0; cd < 4; cd++) {
                bf16x8 vf = ld_bf8(vp + (cd * 16 + l15) * 64 + ((ks * 4 + l4) ^ (l15 & 7)) * 8);
                acc[cd] = __builtin_amdgcn_mfma_f32_16x16x32_bf16(pa, vf, acc[cd], 0, 0, 0);
            }
        }
    }

    psum += __shfl_xor(psum, 16, 64);
    psum += __shfl_xor(psum, 32, 64);
    float ps4[4];
#pragma unroll
    for (int r = 0; r < 4; r++) ps4[r] = __shfl(psum, l4 * 4 + r, 64);

    int b = bh / NHH, h = bh % NHH;
#pragma unroll
    for (int cd = 0; cd < 4; cd++) {
#pragma unroll
        for (int r = 0; r < 4; r++) {
            int qi = qrow0 + l4 * 4 + r;
            float ov = acc[cd][r] / ps4[r];
            o[((size_t)b * SS + qi) * HH + h * HDD + cd * 16 + l15] = f2bf(ov);
        }
    }
}

// ---------------- logits ----------------
__global__ __launch_bounds__(256) void k_logits(const float* __restrict__ enc,
                                                const float* __restrict__ tok,
                                                float* __restrict__ out) {
    int w = threadIdx.x >> 6, lane = threadIdx.x & 63;
    int v = blockIdx.x * 4 + w;
    if (v >= VV) return;
    const float4* tr = (const float4*)(tok + (size_t)v * HH);
    float a[8];
#pragma unroll
    for (int b = 0; b < 8; b++) a[b] = 0.f;
#pragma unroll
    for (int j = 0; j < 3; j++) {
        float4 t4 = tr[lane + 64 * j];
#pragma unroll
        for (int b = 0; b < 8; b++) {
            float4 e4 = *(const float4*)(enc + (size_t)b * HH + (lane + 64 * j) * 4);
            a[b] += t4.x * e4.x + t4.y * e4.y + t4.z * e4.z + t4.w * e4.w;
        }
    }
#pragma unroll
    for (int off = 32; off; off >>= 1)
#pragma unroll
        for (int b = 0; b < 8; b++) a[b] += __shfl_xor(a[b], off, 64);
    if (lane == 0) {
#pragma unroll
        for (int b = 0; b < 8; b++) out[(size_t)b * VV + v] = a[b];
    }
}

extern "C" void kernel_launch(void* const* d_in, const int* in_sizes, int n_in,
                              void* d_out, int out_size, void* d_ws, size_t ws_size,
                              hipStream_t stream) {
    const int* ids = (const int*)d_in[0];
    const float* tok = (const float*)d_in[1];
    const float* pos = (const float*)d_in[2];
    const float* ln1g = (const float*)d_in[3];
    const float* ln1b = (const float*)d_in[4];
    const float* wat = (const float*)d_in[5];
    const float* bat = (const float*)d_in[6];
    const float* wou = (const float*)d_in[7];
    const float* bou = (const float*)d_in[8];
    const float* ln2g = (const float*)d_in[9];
    const float* ln2b = (const float*)d_in[10];
    const float* w1 = (const float*)d_in[11];
    const float* b1 = (const float*)d_in[12];
    const float* w2 = (const float*)d_in[13];
    const float* b2 = (const float*)d_in[14];
    const float* lnfg = (const float*)d_in[15];
    const float* lnfb = (const float*)d_in[16];

    char* ws = (char*)d_ws;
    float* xw = (float*)(ws + 0);                 // f32 residual  [8192,768]
    u16* nb = (u16*)(ws + 25165824);              // bf16 LN out
    u16* qb = (u16*)(ws + 37748736);              // q*0.125*log2e [B,NH,S,HD]
    u16* kb = (u16*)(ws + 50331648);              // k [B,NH,S,HD]
    u16* vb = (u16*)(ws + 62914560);              // v^T [B,NH,HD,S]
    u16* ab = (u16*)(ws + 75497472);              // attn out
    u16* hb = (u16*)(ws + 88080384);              // mlp mid [8192,3072]
    u16* wt = (u16*)(ws + 138412032);             // bf16 transposed weights
    const size_t LSTR = 7077888;
    const size_t WAO = 0, WOO = 1769472, W1O = 2359296, W2O = 4718592;

    float* outf = (float*)d_out;
    float* enc = outf + (size_t)BB * VV;

    k_embed<<<MM, 192, 0, stream>>>(ids, tok, pos, xw);
    k_tcvt<<<dim3(72, 24, 12), 256, 0, stream>>>(wat, wt + WAO, 768, 2304, (size_t)768 * 2304, LSTR);
    k_tcvt<<<dim3(24, 24, 12), 256, 0, stream>>>(wou, wt + WOO, 768, 768, (size_t)768 * 768, LSTR);
    k_tcvt<<<dim3(96, 24, 12), 256, 0, stream>>>(w1, wt + W1O, 768, 3072, (size_t)768 * 3072, LSTR);
    k_tcvt<<<dim3(24, 96, 12), 256, 0, stream>>>(w2, wt + W2O, 3072, 768, (size_t)3072 * 768, LSTR);

    for (int l = 0; l < LL; l++) {
        const u16* wl = wt + (size_t)l * LSTR;
        k_ln<false><<<MM / 4, 256, 0, stream>>>(xw, ln1g + l * HH, ln1b + l * HH, nb, MM, 1, 0);
        k_gemm<0, 2304, 768><<<dim3(18, 64), 256, 0, stream>>>(nb, wl + WAO, bat + (size_t)l * 2304,
                                                               nullptr, qb, kb, vb);
        k_attn<<<dim3(16, 96), 256, 0, stream>>>(qb, kb, vb, ab);
        k_gemm64<768><<<dim3(12, 64), 256, 0, stream>>>(ab, wl + WOO, bou + (size_t)l * HH, xw);
        k_ln<false><<<MM / 4, 256, 0, stream>>>(xw, ln2g + l * HH, ln2b + l * HH, nb, MM, 1, 0);
        k_gemm<2, 3072, 768><<<dim3(24, 64), 256, 0, stream>>>(nb, wl + W1O, b1 + (size_t)l * 3072,
                                                               hb, nullptr, nullptr, nullptr);
        k_gemm64<3072><<<dim3(12, 64), 256, 0, stream>>>(hb, wl + W2O, b2 + (size_t)l * HH, xw);
    }
    k_ln<true><<<2, 256, 0, stream>>>(xw, lnfg, lnfb, enc, BB, SS, SS - 1);
    k_logits<<<(VV + 3) / 4, 256, 0, stream>>>(enc, tok, outf);
}

// Round 15
// 3568.742 us; speedup vs baseline: 1.0076x; 1.0058x over previous
//
#include <hip/hip_runtime.h>
#include <cmath>

typedef unsigned short u16;
typedef __bf16 bf16;
typedef __attribute__((ext_vector_type(8))) bf16 bf16x8;
typedef __attribute__((ext_vector_type(4))) float f32x4;

#define DINL __device__ __forceinline__

#define BB 8
#define SS 1024
#define HH 768
#define LL 12
#define NHH 12
#define HDD 64
#define MM 8192
#define VV 50257

DINL u16 f2bf(float f) {
    unsigned int u = __builtin_bit_cast(unsigned int, f);
    u += 0x7fff + ((u >> 16) & 1);
    return (u16)(u >> 16);
}

DINL bf16x8 ld_bf8(const u16* p) { return *(const bf16x8*)p; }

typedef __attribute__((address_space(1))) unsigned int as1_u32;
typedef __attribute__((address_space(3))) unsigned int as3_u32;

DINL void gllds16(const void* g, void* l) {
    __builtin_amdgcn_global_load_lds((as1_u32*)g, (as3_u32*)l, 16, 0, 0);
}

#define BARRIER()                                   \
    do {                                            \
        asm volatile("" ::: "memory");              \
        __builtin_amdgcn_s_barrier();               \
        asm volatile("" ::: "memory");              \
    } while (0)

// sigmoid-form tanh-GELU: max |err| vs exact-erf gelu ~3e-4 (<< bf16 eps)
DINL float gelu_f(float v) {
    float u = v * (0.7978845608028654f + 0.035677408136300125f * v * v);
    return v * __builtin_amdgcn_rcpf(1.0f + __builtin_amdgcn_exp2f(-2.885390081777927f * u));
}

// XCD-aware block remap: all N-blocks of one M-panel land on the SAME XCD
DINL void xcd_remap(int gx, int& mTile, int& nTile) {
    int i = blockIdx.y * gx + blockIdx.x;
    int xcd = i & 7, j = i >> 3;
    nTile = j % gx;
    mTile = (j / gx) * 8 + xcd;
}

// ---------------- embedding: one block per token, float4 ----------------
__global__ __launch_bounds__(192) void k_embed(const int* __restrict__ ids,
                                               const float* __restrict__ tok,
                                               const float* __restrict__ pos,
                                               float* __restrict__ x) {
    int tk = blockIdx.x;
    int d4 = threadIdx.x;
    int s = tk & (SS - 1);
    int id = ids[tk];
    float4 tv = ((const float4*)(tok + (size_t)id * HH))[d4];
    float4 pv = ((const float4*)(pos + (size_t)s * HH))[d4];
    tv.x += pv.x; tv.y += pv.y; tv.z += pv.z; tv.w += pv.w;
    ((float4*)(x + (size_t)tk * HH))[d4] = tv;
}

// ---------------- transpose + f32->bf16 ----------------
__global__ __launch_bounds__(256) void k_tcvt(const float* __restrict__ src, u16* __restrict__ dst,
                                              int R, int C, size_t sstr, size_t dstr) {
    src += (size_t)blockIdx.z * sstr;
    dst += (size_t)blockIdx.z * dstr;
    __shared__ float t[32][33];
    int tx = threadIdx.x & 31, ty = threadIdx.x >> 5;
    int c0 = blockIdx.x * 32, r0 = blockIdx.y * 32;
#pragma unroll
    for (int p = 0; p < 4; p++)
        t[ty + p * 8][tx] = src[(size_t)(r0 + ty + p * 8) * C + c0 + tx];
    __syncthreads();
#pragma unroll
    for (int p = 0; p < 4; p++)
        dst[(size_t)(c0 + ty + p * 8) * R + r0 + tx] = f2bf(t[tx][ty + p * 8]);
}

// ---------------- layernorm ----------------
template <bool F32OUT>
__global__ __launch_bounds__(256) void k_ln(const float* __restrict__ x, const float* __restrict__ g,
                                            const float* __restrict__ b, void* __restrict__ outp,
                                            int nrows, int rs, int ro) {
    int w = threadIdx.x >> 6, lane = threadIdx.x & 63;
    int row = blockIdx.x * 4 + w;
    if (row >= nrows) return;
    const float4* xr = (const float4*)(x + ((size_t)row * rs + ro) * HH);
    float4 v[3];
    float s = 0.f, s2 = 0.f;
#pragma unroll
    for (int j = 0; j < 3; j++) {
        v[j] = xr[lane + 64 * j];
        s += v[j].x + v[j].y + v[j].z + v[j].w;
        s2 += v[j].x * v[j].x + v[j].y * v[j].y + v[j].z * v[j].z + v[j].w * v[j].w;
    }
#pragma unroll
    for (int off = 32; off; off >>= 1) {
        s += __shfl_xor(s, off, 64);
        s2 += __shfl_xor(s2, off, 64);
    }
    float mu = s * (1.0f / HH);
    float rstd = rsqrtf(s2 * (1.0f / HH) - mu * mu + 1e-5f);
#pragma unroll
    for (int j = 0; j < 3; j++) {
        int d4 = lane + 64 * j;
        float4 gv = ((const float4*)g)[d4];
        float4 bv = ((const float4*)b)[d4];
        float o0 = (v[j].x - mu) * rstd * gv.x + bv.x;
        float o1 = (v[j].y - mu) * rstd * gv.y + bv.y;
        float o2 = (v[j].z - mu) * rstd * gv.z + bv.z;
        float o3 = (v[j].w - mu) * rstd * gv.w + bv.w;
        if (F32OUT) {
            ((float4*)outp)[(size_t)row * (HH / 4) + d4] = make_float4(o0, o1, o2, o3);
        } else {
            ushort4 pk;
            pk.x = f2bf(o0); pk.y = f2bf(o1); pk.z = f2bf(o2); pk.w = f2bf(o3);
            *(ushort4*)((u16*)outp + (size_t)row * HH + d4 * 4) = pk;
        }
    }
}

// ---------------- bf16 GEMM 128x128, BK=32, 3-buffer SINGLE-BARRIER ring ----------------
// (R12 best config: 48KB LDS, 3 blocks/CU, 2-iter prefetch lead, vmcnt(4))
template <int EPI, int N, int K>
__global__ __launch_bounds__(256) void k_gemm(const u16* __restrict__ A, const u16* __restrict__ BT,
                                              const float* __restrict__ bias,
                                              u16* __restrict__ obuf, u16* __restrict__ qb,
                                              u16* __restrict__ kb, u16* __restrict__ vb) {
    __shared__ u16 As[3][128 * 32];
    __shared__ u16 Bs[3][128 * 32];
    const int t = threadIdx.x, w = t >> 6, lane = t & 63;
    const int l15 = lane & 15, l4 = lane >> 4;
    const int wr = w >> 1, wc = w & 1;
    int mT, nT;
    xcd_remap(gridDim.x, mT, nT);
    const int m0 = mT * 128, n0 = nT * 128;
    const int KT = K >> 5;

    f32x4 acc[4][4] = {};

    auto stage = [&](int buf, int kt) {
#pragma unroll
        for (int i = 0; i < 2; i++) {
            int idx = w * 2 + i;
            int row = idx * 16 + (lane >> 2);
            int kc = kt * 32 + (((lane & 3) ^ ((lane >> 3) & 3)) * 8);
            gllds16(A + (size_t)(m0 + row) * K + kc, &As[buf][idx * 512]);
            gllds16(BT + (size_t)(n0 + row) * K + kc, &Bs[buf][idx * 512]);
        }
    };

    stage(0, 0);
    stage(1, 1);
    const int sw = (l15 >> 1) & 3;

    for (int kt = 0; kt < KT; ++kt) {
        if (kt + 1 < KT) asm volatile("s_waitcnt vmcnt(4)" ::: "memory");
        else             asm volatile("s_waitcnt vmcnt(0)" ::: "memory");
        BARRIER();

        const u16* ap = As[kt % 3];
        const u16* bp = Bs[kt % 3];
        bf16x8 af[4], bfr[4];
#pragma unroll
        for (int i = 0; i < 4; i++) af[i] = ld_bf8(ap + (wr * 64 + i * 16 + l15) * 32 + ((l4 ^ sw) * 8));
#pragma unroll
        for (int j = 0; j < 4; j++) bfr[j] = ld_bf8(bp + (wc * 64 + j * 16 + l15) * 32 + ((l4 ^ sw) * 8));

        if (kt + 2 < KT) stage((kt + 2) % 3, kt + 2);

        __builtin_amdgcn_s_setprio(1);
#pragma unroll
        for (int i = 0; i < 4; i++)
#pragma unroll
            for (int j = 0; j < 4; j++)
                acc[i][j] = __builtin_amdgcn_mfma_f32_16x16x32_bf16(af[i], bfr[j], acc[i][j], 0, 0, 0);
        __builtin_amdgcn_s_setprio(0);
    }

#pragma unroll
    for (int i = 0; i < 4; i++) {
#pragma unroll
        for (int j = 0; j < 4; j++) {
#pragma unroll
            for (int r = 0; r < 4; r++) {
                int row = m0 + wr * 64 + i * 16 + l4 * 4 + r;
                int n = n0 + wc * 64 + j * 16 + l15;
                float v = acc[i][j][r] + bias[n];
                if (EPI == 0) {
                    int sg = n / HH, wi = n % HH;
                    int h = wi >> 6, d = wi & 63;
                    int bi = row >> 10, s = row & (SS - 1);
                    size_t bh = (size_t)(bi * NHH + h);
                    if (sg == 0)
                        qb[(bh * SS + s) * HDD + d] = f2bf(v * 0.1803368801111204f);  // 0.125*log2e
                    else if (sg == 1)
                        kb[(bh * SS + s) * HDD + d] = f2bf(v);
                    else
                        vb[(bh * HDD + d) * SS + s] = f2bf(v);
                } else {
                    obuf[(size_t)row * N + n] = f2bf(gelu_f(v));
                }
            }
        }
    }
}

// ---------------- bf16 GEMM 128x64, BK=32, 3-buffer SINGLE-BARRIER ring ----------------
template <int K>
__global__ __launch_bounds__(256) void k_gemm64(const u16* __restrict__ A, const u16* __restrict__ BT,
                                                const float* __restrict__ bias, float* __restrict__ xio) {
    __shared__ u16 As[3][128 * 32];
    __shared__ u16 Bs[3][64 * 32];
    const int t = threadIdx.x, w = t >> 6, lane = t & 63;
    const int l15 = lane & 15, l4 = lane >> 4;
    const int wr = w >> 1, wc = w & 1;
    int mT, nT;
    xcd_remap(gridDim.x, mT, nT);
    const int m0 = mT * 128, n0 = nT * 64;
    const int KT = K >> 5;
    const int N = 768;

    f32x4 acc[4][2] = {};

    auto stage = [&](int buf, int kt) {
        int rr = lane >> 2;
        int kc = kt * 32 + (((lane & 3) ^ ((lane >> 3) & 3)) * 8);
#pragma unroll
        for (int i = 0; i < 2; i++) {
            int idx = w * 2 + i;
            gllds16(A + (size_t)(m0 + idx * 16 + rr) * K + kc, &As[buf][idx * 512]);
        }
        gllds16(BT + (size_t)(n0 + w * 16 + rr) * K + kc, &Bs[buf][w * 512]);
    };

    stage(0, 0);
    stage(1, 1);
    const int sw = (l15 >> 1) & 3;

    for (int kt = 0; kt < KT; ++kt) {
        if (kt + 1 < KT) asm volatile("s_waitcnt vmcnt(3)" ::: "memory");
        else             asm volatile("s_waitcnt vmcnt(0)" ::: "memory");
        BARRIER();

        const u16* ap = As[kt % 3];
        const u16* bp = Bs[kt % 3];
        bf16x8 af[4], bfr[2];
#pragma unroll
        for (int i = 0; i < 4; i++) af[i] = ld_bf8(ap + (wr * 64 + i * 16 + l15) * 32 + ((l4 ^ sw) * 8));
#pragma unroll
        for (int j = 0; j < 2; j++) bfr[j] = ld_bf8(bp + (wc * 32 + j * 16 + l15) * 32 + ((l4 ^ sw) * 8));

        if (kt + 2 < KT) stage((kt + 2) % 3, kt + 2);

        __builtin_amdgcn_s_setprio(1);
#pragma unroll
        for (int i = 0; i < 4; i++)
#pragma unroll
            for (int j = 0; j < 2; j++)
                acc[i][j] = __builtin_amdgcn_mfma_f32_16x16x32_bf16(af[i], bfr[j], acc[i][j], 0, 0, 0);
        __builtin_amdgcn_s_setprio(0);
    }

#pragma unroll
    for (int i = 0; i < 4; i++) {
#pragma unroll
        for (int j = 0; j < 2; j++) {
#pragma unroll
            for (int r = 0; r < 4; r++) {
                int row = m0 + wr * 64 + i * 16 + l4 * 4 + r;
                int n = n0 + wc * 32 + j * 16 + l15;
                xio[(size_t)row * N + n] += acc[i][j][r] + bias[n];
            }
        }
    }
}

// ---------------- flash attention: swapped QK^T (S^T fragments), lane-local softmax ----------------
__global__ __launch_bounds__(256) void k_attn(const u16* __restrict__ q, const u16* __restrict__ k,
                                              const u16* __restrict__ vt, u16* __restrict__ o) {
    int qt = 15 - blockIdx.x;
    int bh = blockIdx.y;
    int w = threadIdx.x >> 6, lane = threadIdx.x & 63;
    int l15 = lane & 15, l4 = lane >> 4;

    __shared__ u16 Ks[3][64 * 64];
    __shared__ u16 Vs[2][64 * 64];
    __shared__ u16 pl[4][16 * 72];
    u16* pw = pl[w];

    const size_t bhq = (size_t)bh * SS * HDD;
    int qrow0 = qt * 64 + w * 16;
    const int myq = qrow0 + l15;

    auto stageK = [&](int slot, int kvb) {
#pragma unroll
        for (int i = 0; i < 2; i++) {
            int rl = w * 16 + i * 8 + (lane >> 3);
            int sc = ((lane & 7) ^ (rl & 7)) * 8;
            gllds16(k + bhq + (size_t)(kvb * 64 + rl) * HDD + sc, &Ks[slot][(w * 16 + i * 8) * 64]);
        }
    };
    auto stageV = [&](int slot, int kvb) {
#pragma unroll
        for (int i = 0; i < 2; i++) {
            int rl = w * 16 + i * 8 + (lane >> 3);
            int sc = ((lane & 7) ^ (rl & 7)) * 8;
            gllds16(vt + ((size_t)bh * HDD + rl) * SS + kvb * 64 + sc, &Vs[slot][(w * 16 + i * 8) * 64]);
        }
    };

    bf16x8 aq[2];
#pragma unroll
    for (int ks = 0; ks < 2; ks++)
        aq[ks] = ld_bf8(q + bhq + (size_t)(qrow0 + l15) * HDD + ks * 32 + l4 * 8);

    f32x4 acc[4] = {};
    float mrun = -1e30f, psum = 0.f;

    stageK(0, 0);
    stageV(0, 0);
    if (qt >= 1) stageK(1, 1);

    for (int kvb = 0; kvb <= qt; ++kvb) {
        if (kvb < qt) asm volatile("s_waitcnt vmcnt(2)" ::: "memory");
        else          asm volatile("s_waitcnt vmcnt(0)" ::: "memory");
        BARRIER();
        if (kvb + 1 <= qt) stageV((kvb + 1) & 1, kvb + 1);
        if (kvb + 2 <= qt) stageK((kvb + 2) % 3, kvb + 2);

        const u16* kp = Ks[kvb % 3];
        const u16* vp = Vs[kvb & 1];

        f32x4 s[4] = {};
#pragma unroll
        for (int c = 0; c < 4; c++) {
#pragma unroll
            for (int ks = 0; ks < 2; ks++) {
                bf16x8 kf = ld_bf8(kp + (c * 16 + l15) * 64 + ((ks * 4 + l4) ^ (l15 & 7)) * 8);
                s[c] = __builtin_amdgcn_mfma_f32_16x16x32_bf16(kf, aq[ks], s[c], 0, 0, 0);
            }
        }
        if (kvb == qt) {
            int kbase = kvb * 64 + l4 * 4;
#pragma unroll
            for (int c = 0; c < 4; c++)
#pragma unroll
                for (int r = 0; r < 4; r++)
                    if (kbase + c * 16 + r > myq) s[c][r] = -1803.3688f;
        }
        float lmax = s[0][0];
#pragma unroll
        for (int c = 0; c < 4; c++)
#pragma unroll
            for (int r = 0; r < 4; r++) lmax = fmaxf(lmax, s[c][r]);
        int ok = (lmax <= mrun + 11.5416f) ? 1 : 0;
        if (!__all(ok)) {
            lmax = fmaxf(lmax, __shfl_xor(lmax, 16, 64));
            lmax = fmaxf(lmax, __shfl_xor(lmax, 32, 64));
            float mnew = fmaxf(mrun, lmax);
            float ef = __builtin_amdgcn_exp2f(mrun - mnew);
            mrun = mnew;
            psum *= ef;
            float ef4[4];
#pragma unroll
            for (int r = 0; r < 4; r++) ef4[r] = __shfl(ef, l4 * 4 + r, 64);
#pragma unroll
            for (int cd = 0; cd < 4; cd++)
#pragma unroll
                for (int r = 0; r < 4; r++) acc[cd][r] *= ef4[r];
        }
#pragma unroll
        for (int c = 0; c < 4; c++) {
            float p0 = __builtin_amdgcn_exp2f(s[c][0] - mrun);
            float p1 = __builtin_amdgcn_exp2f(s[c][1] - mrun);
            float p2 = __builtin_amdgcn_exp2f(s[c][2] - mrun);
            float p3 = __builtin_amdgcn_exp2f(s[c][3] - mrun);
            psum += (p0 + p1) + (p2 + p3);
            ushort4 p4;
            p4.x = f2bf(p0); p4.y = f2bf(p1); p4.z = f2bf(p2); p4.w = f2bf(p3);
            *(ushort4*)(pw + l15 * 72 + c * 16 + l4 * 4) = p4;
        }
#pragma unroll
        for (int ks = 0; ks < 2; ks++) {
            bf16x8 pa = ld_bf8(pw + l15 * 72 + ks * 32 + l4 * 8);
#pragma unroll
            for (int cd = 0; cd < 4; cd++) {
                bf16x8 vf = ld_bf8(vp + (cd * 16 + l15) * 64 + ((ks * 4 + l4) ^ (l15 & 7)) * 8);
                acc[cd] = __builtin_amdgcn_mfma_f32_16x16x32_bf16(pa, vf, acc[cd], 0, 0, 0);
            }
        }
    }

    psum += __shfl_xor(psum, 16, 64);
    psum += __shfl_xor(psum, 32, 64);
    float ps4[4];
#pragma unroll
    for (int r = 0; r < 4; r++) ps4[r] = __shfl(psum, l4 * 4 + r, 64);

    int b = bh / NHH, h = bh % NHH;
#pragma unroll
    for (int cd = 0; cd < 4; cd++) {
#pragma unroll
        for (int r = 0; r < 4; r++) {
            int qi = qrow0 + l4 * 4 + r;
            float ov = acc[cd][r] / ps4[r];
            o[((size_t)b * SS + qi) * HH + h * HDD + cd * 16 + l15] = f2bf(ov);
        }
    }
}

// ---------------- logits ----------------
__global__ __launch_bounds__(256) void k_logits(const float* __restrict__ enc,
                                                const float* __restrict__ tok,
                                                float* __restrict__ out) {
    int w = threadIdx.x >> 6, lane = threadIdx.x & 63;
    int v = blockIdx.x * 4 + w;
    if (v >= VV) return;
    const float4* tr = (const float4*)(tok + (size_t)v * HH);
    float a[8];
#pragma unroll
    for (int b = 0; b < 8; b++) a[b] = 0.f;
#pragma unroll
    for (int j = 0; j < 3; j++) {
        float4 t4 = tr[lane + 64 * j];
#pragma unroll
        for (int b = 0; b < 8; b++) {
            float4 e4 = *(const float4*)(enc + (size_t)b * HH + (lane + 64 * j) * 4);
            a[b] += t4.x * e4.x + t4.y * e4.y + t4.z * e4.z + t4.w * e4.w;
        }
    }
#pragma unroll
    for (int off = 32; off; off >>= 1)
#pragma unroll
        for (int b = 0; b < 8; b++) a[b] += __shfl_xor(a[b], off, 64);
    if (lane == 0) {
#pragma unroll
        for (int b = 0; b < 8; b++) out[(size_t)b * VV + v] = a[b];
    }
}

extern "C" void kernel_launch(void* const* d_in, const int* in_sizes, int n_in,
                              void* d_out, int out_size, void* d_ws, size_t ws_size,
                              hipStream_t stream) {
    const int* ids = (const int*)d_in[0];
    const float* tok = (const float*)d_in[1];
    const float* pos = (const float*)d_in[2];
    const float* ln1g = (const float*)d_in[3];
    const float* ln1b = (const float*)d_in[4];
    const float* wat = (const float*)d_in[5];
    const float* bat = (const float*)d_in[6];
    const float* wou = (const float*)d_in[7];
    const float* bou = (const float*)d_in[8];
    const float* ln2g = (const float*)d_in[9];
    const float* ln2b = (const float*)d_in[10];
    const float* w1 = (const float*)d_in[11];
    const float* b1 = (const float*)d_in[12];
    const float* w2 = (const float*)d_in[13];
    const float* b2 = (const float*)d_in[14];
    const float* lnfg = (const float*)d_in[15];
    const float* lnfb = (const float*)d_in[16];

    char* ws = (char*)d_ws;
    float* xw = (float*)(ws + 0);                 // f32 residual  [8192,768]
    u16* nb = (u16*)(ws + 25165824);              // bf16 LN out
    u16* qb = (u16*)(ws + 37748736);              // q*0.125*log2e [B,NH,S,HD]
    u16* kb = (u16*)(ws + 50331648);              // k [B,NH,S,HD]
    u16* vb = (u16*)(ws + 62914560);              // v^T [B,NH,HD,S]
    u16* ab = (u16*)(ws + 75497472);              // attn out
    u16* hb = (u16*)(ws + 88080384);              // mlp mid [8192,3072]
    u16* wt = (u16*)(ws + 138412032);             // bf16 transposed weights
    const size_t LSTR = 7077888;
    const size_t WAO = 0, WOO = 1769472, W1O = 2359296, W2O = 4718592;

    float* outf = (float*)d_out;
    float* enc = outf + (size_t)BB * VV;

    k_embed<<<MM, 192, 0, stream>>>(ids, tok, pos, xw);
    k_tcvt<<<dim3(72, 24, 12), 256, 0, stream>>>(wat, wt + WAO, 768, 2304, (size_t)768 * 2304, LSTR);
    k_tcvt<<<dim3(24, 24, 12), 256, 0, stream>>>(wou, wt + WOO, 768, 768, (size_t)768 * 768, LSTR);
    k_tcvt<<<dim3(96, 24, 12), 256, 0, stream>>>(w1, wt + W1O, 768, 3072, (size_t)768 * 3072, LSTR);
    k_tcvt<<<dim3(24, 96, 12), 256, 0, stream>>>(w2, wt + W2O, 3072, 768, (size_t)3072 * 768, LSTR);

    for (int l = 0; l < LL; l++) {
        const u16* wl = wt + (size_t)l * LSTR;
        k_ln<false><<<MM / 4, 256, 0, stream>>>(xw, ln1g + l * HH, ln1b + l * HH, nb, MM, 1, 0);
        k_gemm<0, 2304, 768><<<dim3(18, 64), 256, 0, stream>>>(nb, wl + WAO, bat + (size_t)l * 2304,
                                                               nullptr, qb, kb, vb);
        k_attn<<<dim3(16, 96), 256, 0, stream>>>(qb, kb, vb, ab);
        k_gemm64<768><<<dim3(12, 64), 256, 0, stream>>>(ab, wl + WOO, bou + (size_t)l * HH, xw);
        k_ln<false><<<MM / 4, 256, 0, stream>>>(xw, ln2g + l * HH, ln2b + l * HH, nb, MM, 1, 0);
        k_gemm<2, 3072, 768><<<dim3(24, 64), 256, 0, stream>>>(nb, wl + W1O, b1 + (size_t)l * 3072,
                                                               hb, nullptr, nullptr, nullptr);
        k_gemm64<3072><<<dim3(12, 64), 256, 0, stream>>>(hb, wl + W2O, b2 + (size_t)l * HH, xw);
    }
    k_ln<true><<<2, 256, 0, stream>>>(xw, lnfg, lnfb, enc, BB, SS, SS - 1);
    k_logits<<<(VV + 3) / 4, 256, 0, stream>>>(enc, tok, outf);
}